// Round 6
// baseline (89.807 us; speedup 1.0000x reference)
//
#include <hip/hip_runtime.h>
#include <math.h>

#define N_ANCHORS 2048
#define THRESH 0.3f
#define OVERLAP 0.5f
#define NBC 32
#define BLOCK 1024
#define NW 16
#define BUCKET_BASE 32051   // __float_as_uint(0.3f) >> 15; scores in (0.3,1.0] -> idx in [0,461]
#define WMAX 12             // full-matrix NMS path when W <= WMAX (TRI(12)=78 units, 39.9 KB)

// ====== single fused kernel: decode+compact+bucket-rank+matrix-NMS+scatter ======
// 32 blocks (one per batch*class), 1024 threads (16 waves).
// Round-6: word-sequential frontier (14 barriers for W=7) replaced by an
// all-parallel triangular ballot-built suppression matrix + ONE serial wave-0
// fixpoint: 3 barriers total. Frontier retained as W>WMAX fallback.

__global__ __launch_bounds__(BLOCK, 1) void det_mono(
    const float* __restrict__ loc, const float* __restrict__ cls,
    const float* __restrict__ defs, float* __restrict__ out)
{
#pragma clang fp contract(off)
    const int tid  = threadIdx.x;
    const int lane = tid & 63;
    const int wid  = tid >> 6;
    const int bc   = blockIdx.x;
    const int b    = bc >> 2;
    const int c    = bc & 3;

    __shared__ __align__(16) float          csc[2048];      // compacted scores
    __shared__ __align__(16) float2         cbx[2048];      // compacted boxes
    __shared__                unsigned short cid[2048];     // compacted anchor ids
    __shared__ __align__(16) float2         sbox[2048];     // sorted boxes (64-padded)
    __shared__                float          ssc[2048];     // sorted scores
    __shared__                unsigned short sid[2048];     // sorted anchor ids
    __shared__ __align__(16) float4         kbx[2048];      // kept list (frontier path)
    __shared__                unsigned short blist[2048];   // bucket-grouped element ids
    __shared__ int s_hist[512];                             // bucket counts
    __shared__ int s_off[512];                              // bucket offsets, then cursors
    __shared__ __align__(16) unsigned long long mat[78 * 64]; // triangular units (W<=12)
    __shared__ unsigned long long diag[64];                 // frontier: in-word diag rows
    __shared__ unsigned long long deadp[NW];                // frontier: dead partials
    __shared__ unsigned long long keptg[32];                // kept bitmask per word
    __shared__ unsigned long long s_kv[WMAX];               // fixpoint kept words
    __shared__ int s_wsum[NW], s_woff[NW], s_V, s_K;

    float* const outb = out + (size_t)bc * N_ANCHORS * 3;
    {
        float4 z4 = make_float4(0.f, 0.f, 0.f, 0.f);
        float4* ob4 = (float4*)outb;
#pragma unroll 1
        for (int i = tid; i < (N_ANCHORS * 3) / 4; i += BLOCK) ob4[i] = z4;
    }
    if (tid < 32) keptg[tid] = 0ull;
    if (tid < 512) s_hist[tid] = 0;
    if (tid == 0) s_K = 0;

    // ---- decode + softmax (2 anchors / thread) ----
    const int base = tid * 2;
    float c10[10], l4v[4], d4v[4];
    {
        const float2* cp2 = (const float2*)(cls + ((size_t)b * N_ANCHORS + base) * 5);
#pragma unroll
        for (int q = 0; q < 5; ++q) ((float2*)c10)[q] = cp2[q];
        ((float4*)l4v)[0] = *(const float4*)(loc + ((size_t)b * N_ANCHORS + base) * 2);
        ((float4*)d4v)[0] = *(const float4*)(defs + (size_t)base * 2);
    }
    float sc2[2], bs2[2], be2[2];
    int vmask = 0;
#pragma unroll
    for (int k = 0; k < 2; ++k) {
        float x0 = c10[5*k+0], x1 = c10[5*k+1], x2 = c10[5*k+2],
              x3 = c10[5*k+3], x4 = c10[5*k+4];
        float m  = fmaxf(fmaxf(fmaxf(fmaxf(x0, x1), x2), x3), x4);
        float e0 = expf(x0 - m), e1 = expf(x1 - m), e2 = expf(x2 - m),
              e3 = expf(x3 - m), e4 = expf(x4 - m);
        float sum = e0 + e1 + e2 + e3 + e4;
        float ec  = (c == 0) ? e1 : (c == 1) ? e2 : (c == 2) ? e3 : e4;
        float score = ec / sum;
        float l0 = l4v[2*k], l1 = l4v[2*k+1];
        float d0 = d4v[2*k], d1 = d4v[2*k+1];
        float cc = d0 + l0 * d1;
        float w  = d1 * expf(l1);
        sc2[k] = score;
        bs2[k] = cc - 0.5f * w;
        be2[k] = cc + 0.5f * w;
        if (score > THRESH) vmask |= (1 << k);
    }

    // ---- compact (ballot-based block prefix over 16 waves; anchor-ascending order) ----
    const unsigned long long lmlt = (1ull << lane) - 1ull;
    unsigned long long b0 = __ballot(vmask & 1);
    unsigned long long b1 = __ballot(vmask & 2);
    int exc  = __popcll(b0 & lmlt) + __popcll(b1 & lmlt);
    if (lane == 0) s_wsum[wid] = __popcll(b0) + __popcll(b1);
    __syncthreads();
    if (tid == 0) {
        int o = 0;
        for (int w = 0; w < NW; ++w) { s_woff[w] = o; o += s_wsum[w]; }
        s_V = o;
    }
    __syncthreads();
    {
        int off = s_woff[wid] + exc;
#pragma unroll
        for (int k = 0; k < 2; ++k) {
            if (vmask & (1 << k)) {
                csc[off] = sc2[k];
                cbx[off] = make_float2(bs2[k], be2[k]);
                cid[off] = (unsigned short)(base + k);
                off++;
            }
        }
    }
    __syncthreads();
    const int V = s_V;
    const int W = (V + 63) >> 6;
    const int SCend = W << 6;                 // 64-aligned padded extent

    // ---- bucket rank: monotonic bit-buckets + exact in-bucket comparator ----
#pragma unroll 1
    for (int p = tid; p < V; p += BLOCK) {
        unsigned bkt = (__float_as_uint(csc[p]) >> 15) - BUCKET_BASE;
        atomicAdd(&s_hist[bkt], 1);
    }
    __syncthreads();
    if (wid == 0) {       // descending exclusive scan over 512 buckets
        int running = 0;
#pragma unroll 1
        for (int ch = 0; ch < 8; ++ch) {
            int bidx = 511 - ((ch << 6) + lane);       // high buckets first
            int v = s_hist[bidx];
            int incv = v;
#pragma unroll
            for (int d = 1; d < 64; d <<= 1) {
                int t = __shfl_up(incv, d);
                if (lane >= d) incv += t;
            }
            s_off[bidx] = running + incv - v;          // exclusive
            running += __shfl(incv, 63);
        }
    }
    __syncthreads();
#pragma unroll 1
    for (int p = tid; p < V; p += BLOCK) {             // placement (arrival order)
        unsigned bkt = (__float_as_uint(csc[p]) >> 15) - BUCKET_BASE;
        int slot = atomicAdd(&s_off[bkt], 1);
        blist[slot] = (unsigned short)p;
    }
    __syncthreads();
#pragma unroll 1
    for (int p = tid; p < V; p += BLOCK) {             // exact stable rank in bucket
        float s = csc[p];
        unsigned bkt = (__float_as_uint(s) >> 15) - BUCKET_BASE;
        int end = s_off[bkt], cnt = s_hist[bkt];
        int r = end - cnt;                              // base: all higher buckets
#pragma unroll 1
        for (int t = end - cnt; t < end; ++t) {
            int e = blist[t];
            float s2 = csc[e];
            r += (s2 > s || (s2 == s && e < p)) ? 1 : 0;
        }
        sbox[r] = cbx[p];
        ssc[r]  = s;
        sid[r]  = cid[p];
    }
#pragma unroll 1
    for (int i = V + tid; i < SCend; i += BLOCK)
        sbox[i] = make_float2(1e30f, 1e30f);   // sentinel: IoU vs anything = 0
    __syncthreads();

    if (W <= WMAX) {
        // ---- full triangular suppression matrix, ballot-built, zero barriers ----
        const int TRIW = (W * (W + 1)) >> 1;
        {
            int k = 0, w = wid;
            while (w > k) { w -= (k + 1); ++k; }
#pragma unroll 1
            for (int t = wid; t < TRIW; t += NW) {
                const float2 myb = sbox[(w << 6) + lane];   // lane = suppressor (word w)
                const float  myl = myb.y - myb.x;
                unsigned long long myword = 0ull;
#pragma unroll 1
                for (int r = 0; r < 64; ++r) {
                    const float2 vb = sbox[(k << 6) + r];   // victim (uniform read)
                    const float  vl = vb.y - vb.x;
                    float in = fmaxf(fminf(vb.y, myb.y) - fmaxf(vb.x, myb.x), 0.0f);
                    float un = myl + vl - in;               // suppressor len + victim len
                    bool sup = (in > OVERLAP * fmaxf(un, 1e-12f));
                    unsigned long long bal = __ballot(sup);
                    if (w == k) bal &= (1ull << r) - 1ull;  // diagonal: only j < r
                    myword = (lane == r) ? bal : myword;    // lane r keeps victim r's row
                }
                mat[((size_t)t << 6) + lane] = myword;      // t == TRI(k,w)
                w += NW;
                while (w > k) { w -= (k + 1); ++k; }
            }
        }
        __syncthreads();

        // ---- single serial wave-0 greedy fixpoint over all words ----
        if (wid == 0) {
#pragma unroll 1
            for (int g = 0; g < W; ++g) {
                const int gbase = (g * (g + 1)) >> 1;
                unsigned long long dl_or = 0ull;
#pragma unroll 1
                for (int w2 = 0; w2 < g; ++w2)
                    dl_or |= mat[((size_t)(gbase + w2) << 6) + lane] & s_kv[w2];
                const unsigned long long rself = mat[((size_t)(gbase + g) << 6) + lane];
                int rem = V - (g << 6);
                unsigned long long valid = (rem >= 64) ? ~0ull : ((1ull << rem) - 1ull);
                unsigned long long cand = valid & ~__ballot(dl_or != 0ull);
                unsigned long long kw = 0ull;
                while (cand) {                     // in-word greedy levels
                    unsigned long long suppw = __ballot((rself & cand) != 0ull);
                    unsigned long long nk = cand & ~suppw;
                    if (!nk) nk = cand & (~cand + 1ull);   // acyclic: unreachable
                    kw |= nk;
                    unsigned long long ddw = __ballot((rself & nk) != 0ull);
                    cand &= ~(nk | ddw);
                }
                if (lane == 0) { s_kv[g] = kw; keptg[g] = kw; }
            }
        }
        __syncthreads();
    } else {
        // ---- fallback: word-sequential frontier (validated rounds 4-5) ----
#pragma unroll 1
        for (int g = 0; g < W; ++g) {
            const int u = (g << 6) + lane;
            const float2 cb = sbox[u];
            const float  cl = cb.y - cb.x;

            const int K = s_K;
            bool dead = false;
#pragma unroll 1
            for (int i = wid; i < K; i += NW) {
                float4 kb = kbx[i];
                float in = fmaxf(fminf(cb.y, kb.y) - fmaxf(cb.x, kb.x), 0.0f);
                float un = kb.z + cl - in;
                dead |= (in > OVERLAP * fmaxf(un, 1e-12f));
            }
            {
                unsigned long long db = __ballot(dead);
                if (lane == 0) deadp[wid] = db;
            }
#pragma unroll
            for (int q = 0; q < 4; ++q) {
                const int r = (wid << 2) + q;
                const float2 rb = sbox[(g << 6) + r];
                const float  rl = rb.y - rb.x;
                float in = fmaxf(fminf(rb.y, cb.y) - fmaxf(rb.x, cb.x), 0.0f);
                float un = cl + rl - in;
                bool sup = (in > OVERLAP * fmaxf(un, 1e-12f));
                unsigned long long bal = __ballot(sup);
                if (lane == 0) diag[r] = bal & ((1ull << r) - 1ull);
            }
            __syncthreads();

            if (wid == 0) {
                unsigned long long dw = 0ull;
#pragma unroll
                for (int i = 0; i < NW; ++i) dw |= deadp[i];
                const unsigned long long rself = diag[lane];
                int rem = V - (g << 6);
                unsigned long long valid = (rem >= 64) ? ~0ull : ((1ull << rem) - 1ull);
                unsigned long long cand = valid & ~dw;
                unsigned long long kw = 0ull;
                while (cand) {
                    unsigned long long suppw = __ballot((rself & cand) != 0ull);
                    unsigned long long nk = cand & ~suppw;
                    if (!nk) nk = cand & (~cand + 1ull);
                    kw |= nk;
                    unsigned long long ddw = __ballot((rself & nk) != 0ull);
                    cand &= ~(nk | ddw);
                }
                if ((kw >> lane) & 1ull) {
                    int pos = s_K + __popcll(kw & ((1ull << lane) - 1ull));
                    kbx[pos] = make_float4(cb.x, cb.y, cl, 0.f);
                }
                if (lane == 0) { keptg[g] = kw; s_K += __popcll(kw); }
            }
            __syncthreads();
        }
    }

    // ---- scatter kept boxes (in-range filter) ----
#pragma unroll 1
    for (int r = tid; r < V; r += BLOCK) {
        if ((keptg[r >> 6] >> (r & 63)) & 1ull) {
            float2 bx = sbox[r];
            if (bx.x > -10.0f && bx.y < 10.0f) {
                int n = sid[r];
                float* o = outb + (size_t)n * 3;
                o[0] = bx.x;
                o[1] = bx.y;
                o[2] = ssc[r];
            }
        }
    }
}

extern "C" void kernel_launch(void* const* d_in, const int* in_sizes, int n_in,
                              void* d_out, int out_size, void* d_ws, size_t ws_size,
                              hipStream_t stream) {
    const float* loc  = (const float*)d_in[0];  // localizations (8,2048,2)
    const float* cls  = (const float*)d_in[1];  // classifications (8,2048,5)
    const float* defs = (const float*)d_in[2];  // localizations_default (2048,2)
    float* out = (float*)d_out;                 // (8,4,2048,3) fp32
    (void)d_ws; (void)ws_size;
    det_mono<<<NBC, BLOCK, 0, stream>>>(loc, cls, defs, out);
}

// Round 8
// 77.994 us; speedup vs baseline: 1.1515x; 1.1515x over previous
//
#include <hip/hip_runtime.h>
#include <math.h>

#define N_ANCHORS 2048
#define THRESH 0.3f
#define OVERLAP 0.5f
#define NBC 32
#define BLOCK 1024
#define NW 16
#define BUCKET_BASE 32051   // __float_as_uint(0.3f) >> 15; scores in (0.3,1.0] -> idx in [0,461]

// ====== single fused kernel: decode+compact+bucket-rank+frontier-NMS+scatter ======
// 32 blocks (one per batch*class), 1024 threads (16 waves).
// Round-8: resubmit of round-7 (bench infra failure, no measurement).
// Round-5 frontier restored (round-6 matrix NMS was a -12us regression), plus
// one micro-opt: per-word dead-mask reduced via LDS atomicOr in the PARALLEL
// phase (1 read in the serial wave-0 section instead of a 16-read chain).

__global__ __launch_bounds__(BLOCK, 1) void det_mono(
    const float* __restrict__ loc, const float* __restrict__ cls,
    const float* __restrict__ defs, float* __restrict__ out)
{
#pragma clang fp contract(off)
    const int tid  = threadIdx.x;
    const int lane = tid & 63;
    const int wid  = tid >> 6;
    const int bc   = blockIdx.x;
    const int b    = bc >> 2;
    const int c    = bc & 3;

    __shared__ __align__(16) float          csc[2048];      // compacted scores
    __shared__ __align__(16) float2         cbx[2048];      // compacted boxes
    __shared__                unsigned short cid[2048];     // compacted anchor ids
    __shared__ __align__(16) float2         sbox[2048];     // sorted boxes (64-padded)
    __shared__                float          ssc[2048];     // sorted scores
    __shared__                unsigned short sid[2048];     // sorted anchor ids
    __shared__ __align__(16) float4         kbx[2048];      // kept list (s,e,len,_)
    __shared__                unsigned short blist[2048];   // bucket-grouped element ids
    __shared__ int s_hist[512];                             // bucket counts
    __shared__ int s_off[512];                              // bucket offsets, then cursors
    __shared__ unsigned long long diag[64];                 // in-word diagonal rows
    __shared__ unsigned long long s_dw;                     // dead mask (atomicOr-reduced)
    __shared__ unsigned long long keptg[32];                // kept bitmask per word
    __shared__ int s_wsum[NW], s_woff[NW], s_V, s_K;

    float* const outb = out + (size_t)bc * N_ANCHORS * 3;
    {
        float4 z4 = make_float4(0.f, 0.f, 0.f, 0.f);
        float4* ob4 = (float4*)outb;
#pragma unroll 1
        for (int i = tid; i < (N_ANCHORS * 3) / 4; i += BLOCK) ob4[i] = z4;
    }
    if (tid < 32) keptg[tid] = 0ull;
    if (tid < 512) s_hist[tid] = 0;
    if (tid == 0) { s_K = 0; s_dw = 0ull; }

    // ---- decode + softmax (2 anchors / thread) ----
    const int base = tid * 2;
    float c10[10], l4v[4], d4v[4];
    {
        const float2* cp2 = (const float2*)(cls + ((size_t)b * N_ANCHORS + base) * 5);
#pragma unroll
        for (int q = 0; q < 5; ++q) ((float2*)c10)[q] = cp2[q];
        ((float4*)l4v)[0] = *(const float4*)(loc + ((size_t)b * N_ANCHORS + base) * 2);
        ((float4*)d4v)[0] = *(const float4*)(defs + (size_t)base * 2);
    }
    float sc2[2], bs2[2], be2[2];
    int vmask = 0;
#pragma unroll
    for (int k = 0; k < 2; ++k) {
        float x0 = c10[5*k+0], x1 = c10[5*k+1], x2 = c10[5*k+2],
              x3 = c10[5*k+3], x4 = c10[5*k+4];
        float m  = fmaxf(fmaxf(fmaxf(fmaxf(x0, x1), x2), x3), x4);
        float e0 = expf(x0 - m), e1 = expf(x1 - m), e2 = expf(x2 - m),
              e3 = expf(x3 - m), e4 = expf(x4 - m);
        float sum = e0 + e1 + e2 + e3 + e4;
        float ec  = (c == 0) ? e1 : (c == 1) ? e2 : (c == 2) ? e3 : e4;
        float score = ec / sum;
        float l0 = l4v[2*k], l1 = l4v[2*k+1];
        float d0 = d4v[2*k], d1 = d4v[2*k+1];
        float cc = d0 + l0 * d1;
        float w  = d1 * expf(l1);
        sc2[k] = score;
        bs2[k] = cc - 0.5f * w;
        be2[k] = cc + 0.5f * w;
        if (score > THRESH) vmask |= (1 << k);
    }

    // ---- compact (ballot-based block prefix over 16 waves; anchor-ascending order) ----
    const unsigned long long lmlt = (1ull << lane) - 1ull;
    unsigned long long b0 = __ballot(vmask & 1);
    unsigned long long b1 = __ballot(vmask & 2);
    int exc  = __popcll(b0 & lmlt) + __popcll(b1 & lmlt);
    if (lane == 0) s_wsum[wid] = __popcll(b0) + __popcll(b1);
    __syncthreads();
    if (tid == 0) {
        int o = 0;
        for (int w = 0; w < NW; ++w) { s_woff[w] = o; o += s_wsum[w]; }
        s_V = o;
    }
    __syncthreads();
    {
        int off = s_woff[wid] + exc;
#pragma unroll
        for (int k = 0; k < 2; ++k) {
            if (vmask & (1 << k)) {
                csc[off] = sc2[k];
                cbx[off] = make_float2(bs2[k], be2[k]);
                cid[off] = (unsigned short)(base + k);
                off++;
            }
        }
    }
    __syncthreads();
    const int V = s_V;
    const int W = (V + 63) >> 6;
    const int SCend = W << 6;                 // 64-aligned padded extent

    // ---- bucket rank: monotonic bit-buckets + exact in-bucket comparator ----
#pragma unroll 1
    for (int p = tid; p < V; p += BLOCK) {
        unsigned bkt = (__float_as_uint(csc[p]) >> 15) - BUCKET_BASE;
        atomicAdd(&s_hist[bkt], 1);
    }
    __syncthreads();
    if (wid == 0) {       // descending exclusive scan over 512 buckets
        int running = 0;
#pragma unroll 1
        for (int ch = 0; ch < 8; ++ch) {
            int bidx = 511 - ((ch << 6) + lane);       // high buckets first
            int v = s_hist[bidx];
            int incv = v;
#pragma unroll
            for (int d = 1; d < 64; d <<= 1) {
                int t = __shfl_up(incv, d);
                if (lane >= d) incv += t;
            }
            s_off[bidx] = running + incv - v;          // exclusive
            running += __shfl(incv, 63);
        }
    }
    __syncthreads();
#pragma unroll 1
    for (int p = tid; p < V; p += BLOCK) {             // placement (arrival order)
        unsigned bkt = (__float_as_uint(csc[p]) >> 15) - BUCKET_BASE;
        int slot = atomicAdd(&s_off[bkt], 1);
        blist[slot] = (unsigned short)p;
    }
    __syncthreads();
#pragma unroll 1
    for (int p = tid; p < V; p += BLOCK) {             // exact stable rank in bucket
        float s = csc[p];
        unsigned bkt = (__float_as_uint(s) >> 15) - BUCKET_BASE;
        int end = s_off[bkt], cnt = s_hist[bkt];
        int r = end - cnt;                              // base: all higher buckets
#pragma unroll 1
        for (int t = end - cnt; t < end; ++t) {
            int e = blist[t];
            float s2 = csc[e];
            r += (s2 > s || (s2 == s && e < p)) ? 1 : 0;
        }
        sbox[r] = cbx[p];
        ssc[r]  = s;
        sid[r]  = cid[p];
    }
#pragma unroll 1
    for (int i = V + tid; i < SCend; i += BLOCK)
        sbox[i] = make_float2(1e30f, 1e30f);   // sentinel: IoU vs anything = 0
    __syncthreads();

    // ---- frontier NMS: word-sequential, kept-only cross-word scan ----
#pragma unroll 1
    for (int g = 0; g < W; ++g) {
        const int u = (g << 6) + lane;
        const float2 cb = sbox[u];             // this lane's candidate (sentinel-padded)
        const float  cl = cb.y - cb.x;

        // cross-word dead test vs kept list, distributed over 16 waves
        const int K = s_K;
        bool dead = false;
#pragma unroll 1
        for (int i = wid; i < K; i += NW) {
            float4 kb = kbx[i];                // uniform (broadcast) LDS read
            float in = fmaxf(fminf(cb.y, kb.y) - fmaxf(cb.x, kb.x), 0.0f);
            float un = kb.z + cl - in;         // len_kept + len_cand - in
            dead |= (in > OVERLAP * fmaxf(un, 1e-12f));
        }
        {
            unsigned long long db = __ballot(dead);
            if (lane == 0 && db) atomicOr(&s_dw, db);   // parallel-phase reduce
        }

        // in-word diagonal rows via transposed ballot: wave w computes rows 4w..4w+3
#pragma unroll
        for (int q = 0; q < 4; ++q) {
            const int r = (wid << 2) + q;
            const float2 rb = sbox[(g << 6) + r];   // uniform read
            const float  rl = rb.y - rb.x;
            float in = fmaxf(fminf(rb.y, cb.y) - fmaxf(rb.x, cb.x), 0.0f);
            float un = cl + rl - in;                 // len_col + len_row - in
            bool sup = (in > OVERLAP * fmaxf(un, 1e-12f));
            unsigned long long bal = __ballot(sup);
            if (lane == 0) diag[r] = bal & ((1ull << r) - 1ull);   // only j < r
        }
        __syncthreads();

        // wave-0: read reduced dead mask, in-word greedy fixpoint, append kept
        if (wid == 0) {
            unsigned long long dw = s_dw;
            const unsigned long long rself = diag[lane];
            int rem = V - (g << 6);
            unsigned long long valid = (rem >= 64) ? ~0ull : ((1ull << rem) - 1ull);
            unsigned long long cand = valid & ~dw;
            unsigned long long kw = 0ull;
            while (cand) {                     // in-word greedy levels
                unsigned long long suppw = __ballot((rself & cand) != 0ull);
                unsigned long long nk = cand & ~suppw;
                if (!nk) nk = cand & (~cand + 1ull);   // acyclic: unreachable
                kw |= nk;
                unsigned long long ddw = __ballot((rself & nk) != 0ull);
                cand &= ~(nk | ddw);
            }
            if ((kw >> lane) & 1ull) {
                int pos = s_K + __popcll(kw & ((1ull << lane) - 1ull));
                kbx[pos] = make_float4(cb.x, cb.y, cl, 0.f);
            }
            if (lane == 0) { keptg[g] = kw; s_K += __popcll(kw); s_dw = 0ull; }
        }
        __syncthreads();
    }

    // ---- scatter kept boxes (in-range filter) ----
#pragma unroll 1
    for (int r = tid; r < V; r += BLOCK) {
        if ((keptg[r >> 6] >> (r & 63)) & 1ull) {
            float2 bx = sbox[r];
            if (bx.x > -10.0f && bx.y < 10.0f) {
                int n = sid[r];
                float* o = outb + (size_t)n * 3;
                o[0] = bx.x;
                o[1] = bx.y;
                o[2] = ssc[r];
            }
        }
    }
}

extern "C" void kernel_launch(void* const* d_in, const int* in_sizes, int n_in,
                              void* d_out, int out_size, void* d_ws, size_t ws_size,
                              hipStream_t stream) {
    const float* loc  = (const float*)d_in[0];  // localizations (8,2048,2)
    const float* cls  = (const float*)d_in[1];  // classifications (8,2048,5)
    const float* defs = (const float*)d_in[2];  // localizations_default (2048,2)
    float* out = (float*)d_out;                 // (8,4,2048,3) fp32
    (void)d_ws; (void)ws_size;
    det_mono<<<NBC, BLOCK, 0, stream>>>(loc, cls, defs, out);
}